// Round 6
// baseline (375.792 us; speedup 1.0000x reference)
//
#include <hip/hip_runtime.h>
#include <hip/hip_bf16.h>

typedef __bf16 bf16x8 __attribute__((ext_vector_type(8)));
typedef float floatx4 __attribute__((ext_vector_type(4)));

#define Bc 4
#define Lc 2048
#define Sc 2048
#define Hc 16
#define Ec 64
#define Dc 64
#define QB 128
#define NQTB (Lc/QB)   /* 16 */

__device__ __forceinline__ bf16x8 pack8f(const float* f){
  bf16x8 r;
  #pragma unroll
  for (int i=0;i<8;++i) r[i] = (__bf16)f[i];
  return r;
}

__global__ __launch_bounds__(256, 4)
void fa_fwd(const float* __restrict__ Q, const float* __restrict__ K,
            const float* __restrict__ V, float* __restrict__ O)
{
  // XCD-contiguous remap (1024 % 8 == 0, bijective)
  int nid = blockIdx.x;
  int bid = (nid & 7) * ((int)gridDim.x >> 3) + (nid >> 3);
  int qtb = bid & (NQTB - 1);
  int h  = (bid >> 4) & (Hc - 1);
  int b  = bid >> 8;

  int tid  = threadIdx.x;
  int w    = tid >> 6;
  int lane = tid & 63;
  int lg   = lane >> 4;   // 0..3
  int lr   = lane & 15;   // 0..15

  __shared__ __align__(16) char Kl[2][64*128];
  __shared__ __align__(16) char Vl[2][64*128];    // transposed: Vt[d][k], swizzled
  __shared__ __align__(16) char Pl[4][16*64*2];   // per-wave P buffer, reused by both q-sets
  char* Pw = Pl[w];

  const int Q0  = qtb * QB;
  const int q0w = Q0 + w*32;        // this wave's first q row (32 rows)

  // ---- Q fragments for both 16-row sets (A-layout: row=lr, k=32*c+8*lg+j) ----
  bf16x8 aq[2][2];
  #pragma unroll
  for (int s2=0; s2<2; ++s2) {
    const float* qp = Q + ((size_t)(b*Lc + q0w + s2*16 + lr)*Hc + h)*Ec;
    float tmp[8];
    *(float4*)(tmp)   = *(const float4*)(qp + lg*8);
    *(float4*)(tmp+4) = *(const float4*)(qp + lg*8 + 4);
    aq[s2][0] = pack8f(tmp);
    *(float4*)(tmp)   = *(const float4*)(qp + 32 + lg*8);
    *(float4*)(tmp+4) = *(const float4*)(qp + 32 + lg*8 + 4);
    aq[s2][1] = pack8f(tmp);
  }

  floatx4 o[2][4];
  float m[2][4], lsum[2][4];
  #pragma unroll
  for (int s2=0; s2<2; ++s2)
    #pragma unroll
    for (int i=0;i<4;++i){ o[s2][i] = (floatx4){0.f,0.f,0.f,0.f}; m[s2][i] = -3.0e38f; lsum[s2][i] = 0.f; }

  // ---- staging thread mapping (round-5 verbatim) ----
  const int skr = tid >> 2, seg = tid & 3;   // K: row skr (0..63), 16-float chunk seg
  const int sd  = tid & 63, skb = tid >> 6;  // V: d-column sd (0..63), key-block skb (16 keys)
  const unsigned xk = (skr & 7) << 4;
  const unsigned xv = (sd  & 7) << 4;

  const float* Kb = K + ((size_t)(b*Sc)*Hc + h)*Ec;
  const float* Vb = V + ((size_t)(b*Sc)*Hc + h)*Dc;

  float kf[16], vf[16];
  // prefetch tile 0 into registers
  {
    const float* ks = Kb + (size_t)skr*Hc*Ec + seg*16;
    *(float4*)(kf)    = *(const float4*)(ks);
    *(float4*)(kf+4)  = *(const float4*)(ks+4);
    *(float4*)(kf+8)  = *(const float4*)(ks+8);
    *(float4*)(kf+12) = *(const float4*)(ks+12);
    const float* vs = Vb + (size_t)(skb*16)*Hc*Dc + sd;
    #pragma unroll
    for (int i=0;i<16;++i) vf[i] = vs[(size_t)i*Hc*Dc];
  }

  const int nt = 2*qtb + 2;
  for (int t = 0; t < nt; ++t) {
    char* Kcur = Kl[t&1];
    char* Vcur = Vl[t&1];

    // ---- write staged tile from registers (bf16, swizzled, wide) ----
    *(bf16x8*)(Kcur + skr*128 + ((seg*32)      ^ xk)) = pack8f(kf);
    *(bf16x8*)(Kcur + skr*128 + ((seg*32 + 16) ^ xk)) = pack8f(kf+8);
    *(bf16x8*)(Vcur + sd*128  + ((skb*32)      ^ xv)) = pack8f(vf);
    *(bf16x8*)(Vcur + sd*128  + ((skb*32 + 16) ^ xv)) = pack8f(vf+8);
    __syncthreads();

    // ---- async-stage split: issue next tile's global loads now ----
    if (t+1 < nt) {
      const float* ks = Kb + (size_t)((t+1)*64 + skr)*Hc*Ec + seg*16;
      *(float4*)(kf)    = *(const float4*)(ks);
      *(float4*)(kf+4)  = *(const float4*)(ks+4);
      *(float4*)(kf+8)  = *(const float4*)(ks+8);
      *(float4*)(kf+12) = *(const float4*)(ks+12);
      const float* vs = Vb + (size_t)((t+1)*64 + skb*16)*Hc*Dc + sd;
      #pragma unroll
      for (int i=0;i<16;++i) vf[i] = vs[(size_t)i*Hc*Dc];
    }

    // ---- per-wave skip: tile entirely above this wave's rows ----
    if (t*64 <= q0w + 31) {
      const int t64 = t*64;
      const bool needmask = (t64 + 63 > q0w);

      #pragma unroll
      for (int s2=0; s2<2; ++s2) {
        // ---- QK^T: S[16 q][64 k]  (round-5 verbatim, q-set offset) ----
        floatx4 s[4];
        #pragma unroll
        for (int nf=0; nf<4; ++nf) {
          int kr = nf*16 + lr;
          unsigned xr = (kr & 7) << 4;
          const char* kp = Kcur + kr*128;
          bf16x8 b0 = *(const bf16x8*)(kp + ((lg*16)      ^ xr));
          bf16x8 b1 = *(const bf16x8*)(kp + ((64 + lg*16) ^ xr));
          floatx4 acc = (floatx4){0.f,0.f,0.f,0.f};
          acc = __builtin_amdgcn_mfma_f32_16x16x32_bf16(aq[s2][0], b0, acc, 0, 0, 0);
          acc = __builtin_amdgcn_mfma_f32_16x16x32_bf16(aq[s2][1], b1, acc, 0, 0, 0);
          s[nf] = acc;
        }

        // ---- scale + causal mask (global indices; identical arithmetic) ----
        const int qq = q0w + s2*16 + lg*4;   // + r below
        #pragma unroll
        for (int nf=0; nf<4; ++nf)
          #pragma unroll
          for (int r=0; r<4; ++r) {
            float v = s[nf][r] * 0.125f;
            if (needmask && (t64 + nf*16 + lr > qq + r)) v = -3.0e38f;
            s[nf][r] = v;
          }

        // ---- online softmax (rows live in 16-lane groups) ----
        float mx[4], rs[4], al[4];
        #pragma unroll
        for (int r=0;r<4;++r)
          mx[r] = fmaxf(fmaxf(s[0][r], s[1][r]), fmaxf(s[2][r], s[3][r]));
        #pragma unroll
        for (int st=1; st<16; st<<=1)
          #pragma unroll
          for (int r=0;r<4;++r)
            mx[r] = fmaxf(mx[r], __shfl_xor(mx[r], st));
        #pragma unroll
        for (int r=0;r<4;++r) {
          float mn = fmaxf(m[s2][r], mx[r]);
          al[r] = __expf(m[s2][r] - mn);
          m[s2][r] = mn;
          rs[r] = 0.f;
        }
        #pragma unroll
        for (int nf=0; nf<4; ++nf)
          #pragma unroll
          for (int r=0;r<4;++r) {
            float p = __expf(s[nf][r] - m[s2][r]);
            rs[r] += p;
            s[nf][r] = p;
          }
        #pragma unroll
        for (int st=1; st<16; st<<=1)
          #pragma unroll
          for (int r=0;r<4;++r)
            rs[r] += __shfl_xor(rs[r], st);
        #pragma unroll
        for (int r=0;r<4;++r) lsum[s2][r] = lsum[s2][r]*al[r] + rs[r];
        #pragma unroll
        for (int df=0; df<4; ++df)
          #pragma unroll
          for (int r=0;r<4;++r) o[s2][df][r] *= al[r];

        // ---- P: D-layout regs -> bf16 LDS (per-wave, reused per set) ----
        #pragma unroll
        for (int nf=0; nf<4; ++nf)
          #pragma unroll
          for (int r=0;r<4;++r) {
            int q = lg*4 + r;
            int k = nf*16 + lr;
            *(__bf16*)(Pw + q*128 + ((k*2) ^ ((q&7)<<4))) = (__bf16)s[nf][r];
          }

        // ---- PV: O[16 q][64 d] += P @ V ----
        {
          unsigned xq = (lr & 7) << 4;
          const char* pp = Pw + lr*128;
          bf16x8 pa0 = *(const bf16x8*)(pp + ((lg*16)      ^ xq));
          bf16x8 pa1 = *(const bf16x8*)(pp + ((64 + lg*16) ^ xq));
          #pragma unroll
          for (int df=0; df<4; ++df) {
            int d = df*16 + lr;
            unsigned xd = (d & 7) << 4;
            const char* vp = Vcur + d*128;
            bf16x8 vb0 = *(const bf16x8*)(vp + ((lg*16)      ^ xd));
            bf16x8 vb1 = *(const bf16x8*)(vp + ((64 + lg*16) ^ xd));
            o[s2][df] = __builtin_amdgcn_mfma_f32_16x16x32_bf16(pa0, vb0, o[s2][df], 0, 0, 0);
            o[s2][df] = __builtin_amdgcn_mfma_f32_16x16x32_bf16(pa1, vb1, o[s2][df], 0, 0, 0);
          }
        }
      } // q-set loop
    }
    __syncthreads();
  }

  // ---- epilogue: O / lsum -> global ----
  #pragma unroll
  for (int s2=0; s2<2; ++s2)
    #pragma unroll
    for (int r=0;r<4;++r) {
      float inv = 1.0f / lsum[s2][r];
      int qg = q0w + s2*16 + lg*4 + r;
      float* op = O + ((size_t)(b*Lc + qg)*Hc + h)*Dc;
      #pragma unroll
      for (int df=0; df<4; ++df)
        op[df*16 + lr] = o[s2][df][r] * inv;
    }
}

extern "C" void kernel_launch(void* const* d_in, const int* in_sizes, int n_in,
                              void* d_out, int out_size, void* d_ws, size_t ws_size,
                              hipStream_t stream) {
  const float* Q = (const float*)d_in[0];
  const float* K = (const float*)d_in[1];
  const float* V = (const float*)d_in[2];
  float* O = (float*)d_out;
  dim3 grid(Bc * Hc * NQTB);   // 1024 blocks
  dim3 block(256);
  fa_fwd<<<grid, block, 0, stream>>>(Q, K, V, O);
}

// Round 7
// 192.243 us; speedup vs baseline: 1.9548x; 1.9548x over previous
//
#include <hip/hip_runtime.h>
#include <hip/hip_bf16.h>

typedef __bf16 bf16x8 __attribute__((ext_vector_type(8)));
typedef float floatx4 __attribute__((ext_vector_type(4)));

#define Bc 4
#define Lc 2048
#define Sc 2048
#define Hc 16
#define Ec 64
#define Dc 64
#define QB 128
#define NQTB (Lc/QB)   /* 16 */

__device__ __forceinline__ bf16x8 pack8f(const float* f){
  bf16x8 r;
  #pragma unroll
  for (int i=0;i<8;++i) r[i] = (__bf16)f[i];
  return r;
}

__global__ __launch_bounds__(256)
void fa_fwd(const float* __restrict__ Q, const float* __restrict__ K,
            const float* __restrict__ V, float* __restrict__ O)
{
  // XCD-contiguous remap (1024 % 8 == 0, bijective)
  int nid = blockIdx.x;
  int bid = (nid & 7) * ((int)gridDim.x >> 3) + (nid >> 3);
  int qtb = bid & (NQTB - 1);
  int h  = (bid >> 4) & (Hc - 1);
  int b  = bid >> 8;

  int tid  = threadIdx.x;
  int w    = tid >> 6;
  int lane = tid & 63;
  int lg   = lane >> 4;   // 0..3
  int lr   = lane & 15;   // 0..15

  __shared__ __align__(16) char Kl[2][64*128];
  __shared__ __align__(16) char Vl[2][64*128];    // transposed: Vt[d][k], swizzled
  __shared__ __align__(16) char Pl[4][16*64*2];   // per-wave P buffer, reused by both q-sets
  char* Pw = Pl[w];

  const int Q0  = qtb * QB;
  const int q0w = Q0 + w*32;        // this wave's first q row (32 rows)

  // ---- Q fragments, scale 1/8 folded in (power-of-2: bit-identical softmax) ----
  bf16x8 aq[2][2];
  #pragma unroll
  for (int s2=0; s2<2; ++s2) {
    const float* qp = Q + ((size_t)(b*Lc + q0w + s2*16 + lr)*Hc + h)*Ec;
    float tmp[8];
    #pragma unroll
    for (int c=0; c<2; ++c) {
      *(float4*)(tmp)   = *(const float4*)(qp + c*32 + lg*8);
      *(float4*)(tmp+4) = *(const float4*)(qp + c*32 + lg*8 + 4);
      #pragma unroll
      for (int i=0;i<8;++i) tmp[i] *= 0.125f;
      aq[s2][c] = pack8f(tmp);
    }
  }

  floatx4 o[2][4];
  float m[2][4], lsum[2][4];
  #pragma unroll
  for (int s2=0; s2<2; ++s2)
    #pragma unroll
    for (int i=0;i<4;++i){ o[s2][i] = (floatx4){0.f,0.f,0.f,0.f}; m[s2][i] = -3.0e38f; lsum[s2][i] = 0.f; }

  // ---- staging thread mapping (round-5 verbatim) ----
  const int skr = tid >> 2, seg = tid & 3;   // K: row skr (0..63), 16-float chunk seg
  const int sd  = tid & 63, skb = tid >> 6;  // V: d-column sd (0..63), key-block skb (16 keys)
  const unsigned xk = (skr & 7) << 4;
  const unsigned xv = (sd  & 7) << 4;

  const float* Kb = K + ((size_t)(b*Sc)*Hc + h)*Ec;
  const float* Vb = V + ((size_t)(b*Sc)*Hc + h)*Dc;

  float kf[16], vf[16];
  // prefetch tile 0 into registers
  {
    const float* ks = Kb + (size_t)skr*Hc*Ec + seg*16;
    *(float4*)(kf)    = *(const float4*)(ks);
    *(float4*)(kf+4)  = *(const float4*)(ks+4);
    *(float4*)(kf+8)  = *(const float4*)(ks+8);
    *(float4*)(kf+12) = *(const float4*)(ks+12);
    const float* vs = Vb + (size_t)(skb*16)*Hc*Dc + sd;
    #pragma unroll
    for (int i=0;i<16;++i) vf[i] = vs[(size_t)i*Hc*Dc];
  }

  const int nt = 2*qtb + 2;
  for (int t = 0; t < nt; ++t) {
    char* Kcur = Kl[t&1];
    char* Vcur = Vl[t&1];

    // ---- write staged tile from registers (bf16, swizzled, wide) ----
    *(bf16x8*)(Kcur + skr*128 + ((seg*32)      ^ xk)) = pack8f(kf);
    *(bf16x8*)(Kcur + skr*128 + ((seg*32 + 16) ^ xk)) = pack8f(kf+8);
    *(bf16x8*)(Vcur + sd*128  + ((skb*32)      ^ xv)) = pack8f(vf);
    *(bf16x8*)(Vcur + sd*128  + ((skb*32 + 16) ^ xv)) = pack8f(vf+8);
    __syncthreads();

    // ---- async-stage split: issue next tile's global loads now ----
    if (t+1 < nt) {
      const float* ks = Kb + (size_t)((t+1)*64 + skr)*Hc*Ec + seg*16;
      *(float4*)(kf)    = *(const float4*)(ks);
      *(float4*)(kf+4)  = *(const float4*)(ks+4);
      *(float4*)(kf+8)  = *(const float4*)(ks+8);
      *(float4*)(kf+12) = *(const float4*)(ks+12);
      const float* vs = Vb + (size_t)((t+1)*64 + skb*16)*Hc*Dc + sd;
      #pragma unroll
      for (int i=0;i<16;++i) vf[i] = vs[(size_t)i*Hc*Dc];
    }

    // ---- per-wave skip: tile entirely above this wave's rows ----
    if (t*64 <= q0w + 31) {
      const int t64 = t*64;
      const bool needmask = (t64 + 63 > q0w);

      #pragma unroll
      for (int s2=0; s2<2; ++s2) {
        // ---- QK^T: S[16 q][64 k] ----
        floatx4 s[4];
        #pragma unroll
        for (int nf=0; nf<4; ++nf) {
          int kr = nf*16 + lr;
          unsigned xr = (kr & 7) << 4;
          const char* kp = Kcur + kr*128;
          bf16x8 b0 = *(const bf16x8*)(kp + ((lg*16)      ^ xr));
          bf16x8 b1 = *(const bf16x8*)(kp + ((64 + lg*16) ^ xr));
          floatx4 acc = (floatx4){0.f,0.f,0.f,0.f};
          acc = __builtin_amdgcn_mfma_f32_16x16x32_bf16(aq[s2][0], b0, acc, 0, 0, 0);
          acc = __builtin_amdgcn_mfma_f32_16x16x32_bf16(aq[s2][1], b1, acc, 0, 0, 0);
          s[nf] = acc;
        }

        // ---- causal mask (scale already folded into Q) ----
        if (needmask) {
          const int qq = q0w + s2*16 + lg*4;
          #pragma unroll
          for (int nf=0; nf<4; ++nf)
            #pragma unroll
            for (int r=0; r<4; ++r)
              if (t64 + nf*16 + lr > qq + r) s[nf][r] = -3.0e38f;
        }

        // ---- online softmax (rows live in 16-lane groups) ----
        float mx[4], rs[4], al[4];
        #pragma unroll
        for (int r=0;r<4;++r)
          mx[r] = fmaxf(fmaxf(s[0][r], s[1][r]), fmaxf(s[2][r], s[3][r]));
        #pragma unroll
        for (int st=1; st<16; st<<=1)
          #pragma unroll
          for (int r=0;r<4;++r)
            mx[r] = fmaxf(mx[r], __shfl_xor(mx[r], st));
        #pragma unroll
        for (int r=0;r<4;++r) {
          float mn = fmaxf(m[s2][r], mx[r]);
          al[r] = __expf(m[s2][r] - mn);
          m[s2][r] = mn;
          rs[r] = 0.f;
        }
        #pragma unroll
        for (int nf=0; nf<4; ++nf)
          #pragma unroll
          for (int r=0;r<4;++r) {
            float p = __expf(s[nf][r] - m[s2][r]);
            rs[r] += p;
            s[nf][r] = p;
          }
        #pragma unroll
        for (int st=1; st<16; st<<=1)
          #pragma unroll
          for (int r=0;r<4;++r)
            rs[r] += __shfl_xor(rs[r], st);
        #pragma unroll
        for (int r=0;r<4;++r) lsum[s2][r] = lsum[s2][r]*al[r] + rs[r];
        #pragma unroll
        for (int df=0; df<4; ++df)
          #pragma unroll
          for (int r=0;r<4;++r) o[s2][df][r] *= al[r];

        // ---- P: D-layout regs -> bf16 LDS (per-wave, reused per set) ----
        #pragma unroll
        for (int nf=0; nf<4; ++nf)
          #pragma unroll
          for (int r=0;r<4;++r) {
            int q = lg*4 + r;
            int k = nf*16 + lr;
            *(__bf16*)(Pw + q*128 + ((k*2) ^ ((q&7)<<4))) = (__bf16)s[nf][r];
          }

        // ---- PV: O[16 q][64 d] += P @ V ----
        {
          unsigned xq = (lr & 7) << 4;
          const char* pp = Pw + lr*128;
          bf16x8 pa0 = *(const bf16x8*)(pp + ((lg*16)      ^ xq));
          bf16x8 pa1 = *(const bf16x8*)(pp + ((64 + lg*16) ^ xq));
          #pragma unroll
          for (int df=0; df<4; ++df) {
            int d = df*16 + lr;
            unsigned xd = (d & 7) << 4;
            const char* vp = Vcur + d*128;
            bf16x8 vb0 = *(const bf16x8*)(vp + ((lg*16)      ^ xd));
            bf16x8 vb1 = *(const bf16x8*)(vp + ((64 + lg*16) ^ xd));
            o[s2][df] = __builtin_amdgcn_mfma_f32_16x16x32_bf16(pa0, vb0, o[s2][df], 0, 0, 0);
            o[s2][df] = __builtin_amdgcn_mfma_f32_16x16x32_bf16(pa1, vb1, o[s2][df], 0, 0, 0);
          }
        }
      } // q-set loop
    }
    __syncthreads();
  }

  // ---- epilogue: O / lsum -> global ----
  #pragma unroll
  for (int s2=0; s2<2; ++s2)
    #pragma unroll
    for (int r=0;r<4;++r) {
      float inv = 1.0f / lsum[s2][r];
      int qg = q0w + s2*16 + lg*4 + r;
      float* op = O + ((size_t)(b*Lc + qg)*Hc + h)*Dc;
      #pragma unroll
      for (int df=0; df<4; ++df)
        op[df*16 + lr] = o[s2][df][r] * inv;
    }
}

extern "C" void kernel_launch(void* const* d_in, const int* in_sizes, int n_in,
                              void* d_out, int out_size, void* d_ws, size_t ws_size,
                              hipStream_t stream) {
  const float* Q = (const float*)d_in[0];
  const float* K = (const float*)d_in[1];
  const float* V = (const float*)d_in[2];
  float* O = (float*)d_out;
  dim3 grid(Bc * Hc * NQTB);   // 1024 blocks
  dim3 block(256);
  fa_fwd<<<grid, block, 0, stream>>>(Q, K, V, O);
}

// Round 8
// 149.210 us; speedup vs baseline: 2.5186x; 1.2884x over previous
//
#include <hip/hip_runtime.h>
#include <hip/hip_bf16.h>

typedef __bf16 bf16x8 __attribute__((ext_vector_type(8)));
typedef float floatx4 __attribute__((ext_vector_type(4)));

#define Bc 4
#define Lc 2048
#define Sc 2048
#define Hc 16
#define Ec 64
#define Dc 64
#define NQT (Lc/64)      /* 32 strips of 64 q-rows */
#define NPAIR (NQT/2)    /* 16 pair-ids */

__device__ __forceinline__ bf16x8 pack8f(const float* f){
  bf16x8 r;
  #pragma unroll
  for (int i=0;i<8;++i) r[i] = (__bf16)f[i];
  return r;
}

__global__ __launch_bounds__(256)
void fa_fwd(const float* __restrict__ Q, const float* __restrict__ K,
            const float* __restrict__ V, float* __restrict__ O)
{
  // XCD-contiguous remap (1024 % 8 == 0, bijective)
  int nid = blockIdx.x;
  int bid = (nid & 7) * ((int)gridDim.x >> 3) + (nid >> 3);
  int pid = bid & (NPAIR - 1);
  int h  = (bid >> 4) & (Hc - 1);
  int b  = bid >> 8;

  int tid  = threadIdx.x;
  int w    = tid >> 6;
  int lane = tid & 63;
  int lg   = lane >> 4;   // 0..3
  int lr   = lane & 15;   // 0..15

  __shared__ __align__(16) char Kl[2][64*128];
  __shared__ __align__(16) char Vl[2][64*128];    // transposed: Vt[d][k], swizzled
  __shared__ __align__(16) char Pl[4][16*64*2];   // per-wave P buffer
  char* Pw = Pl[w];

  // ---- staging thread mapping (round-5 verbatim) ----
  const int skr = tid >> 2, seg = tid & 3;   // K: row skr (0..63), 16-float chunk seg
  const int sd  = tid & 63, skb = tid >> 6;  // V: d-column sd (0..63), key-block skb (16 keys)
  const unsigned xk = (skr & 7) << 4;
  const unsigned xv = (sd  & 7) << 4;

  const float* Kb = K + ((size_t)(b*Sc)*Hc + h)*Ec;
  const float* Vb = V + ((size_t)(b*Sc)*Hc + h)*Dc;

  float kf[16], vf[16];

  // ---- two complementary causal strips: work = (pid+1) + (32-pid) = 33 tiles, constant ----
  #pragma unroll 1
  for (int pass=0; pass<2; ++pass) {
    const int qt = pass ? (NQT-1-pid) : pid;

    // ---- Q fragments, scale 1/8 folded in (A-layout: row=lr, k=32*c+8*lg+j) ----
    const int qrow = qt*64 + w*16 + lr;
    const float* qp = Q + ((size_t)(b*Lc + qrow)*Hc + h)*Ec;
    bf16x8 aq[2];
    {
      float tmp[8];
      #pragma unroll
      for (int c=0; c<2; ++c) {
        *(float4*)(tmp)   = *(const float4*)(qp + c*32 + lg*8);
        *(float4*)(tmp+4) = *(const float4*)(qp + c*32 + lg*8 + 4);
        #pragma unroll
        for (int i=0;i<8;++i) tmp[i] *= 0.125f;
        aq[c] = pack8f(tmp);
      }
    }

    floatx4 o[4];
    float m[4], lsum[4];
    #pragma unroll
    for (int i=0;i<4;++i){ o[i] = (floatx4){0.f,0.f,0.f,0.f}; m[i] = -3.0e38f; lsum[i] = 0.f; }

    // prefetch tile 0 into registers
    {
      const float* ks = Kb + (size_t)skr*Hc*Ec + seg*16;
      *(float4*)(kf)    = *(const float4*)(ks);
      *(float4*)(kf+4)  = *(const float4*)(ks+4);
      *(float4*)(kf+8)  = *(const float4*)(ks+8);
      *(float4*)(kf+12) = *(const float4*)(ks+12);
      const float* vs = Vb + (size_t)(skb*16)*Hc*Dc + sd;
      #pragma unroll
      for (int i=0;i<16;++i) vf[i] = vs[(size_t)i*Hc*Dc];
    }

    const int nt = qt + 1;
    for (int t = 0; t < nt; ++t) {
      char* Kcur = Kl[t&1];
      char* Vcur = Vl[t&1];

      // ---- write staged tile from registers (bf16, swizzled, wide) ----
      *(bf16x8*)(Kcur + skr*128 + ((seg*32)      ^ xk)) = pack8f(kf);
      *(bf16x8*)(Kcur + skr*128 + ((seg*32 + 16) ^ xk)) = pack8f(kf+8);
      *(bf16x8*)(Vcur + sd*128  + ((skb*32)      ^ xv)) = pack8f(vf);
      *(bf16x8*)(Vcur + sd*128  + ((skb*32 + 16) ^ xv)) = pack8f(vf+8);
      __syncthreads();

      // ---- async-stage split: issue next tile's global loads now ----
      if (t+1 < nt) {
        const float* ks = Kb + (size_t)((t+1)*64 + skr)*Hc*Ec + seg*16;
        *(float4*)(kf)    = *(const float4*)(ks);
        *(float4*)(kf+4)  = *(const float4*)(ks+4);
        *(float4*)(kf+8)  = *(const float4*)(ks+8);
        *(float4*)(kf+12) = *(const float4*)(ks+12);
        const float* vs = Vb + (size_t)((t+1)*64 + skb*16)*Hc*Dc + sd;
        #pragma unroll
        for (int i=0;i<16;++i) vf[i] = vs[(size_t)i*Hc*Dc];
      }

      // ---- QK^T: S[16 q][64 k] ----
      floatx4 s[4];
      #pragma unroll
      for (int nf=0; nf<4; ++nf) {
        int kr = nf*16 + lr;
        unsigned xr = (kr & 7) << 4;
        const char* kp = Kcur + kr*128;
        bf16x8 b0 = *(const bf16x8*)(kp + ((lg*16)      ^ xr));
        bf16x8 b1 = *(const bf16x8*)(kp + ((64 + lg*16) ^ xr));
        floatx4 acc = (floatx4){0.f,0.f,0.f,0.f};
        acc = __builtin_amdgcn_mfma_f32_16x16x32_bf16(aq[0], b0, acc, 0, 0, 0);
        acc = __builtin_amdgcn_mfma_f32_16x16x32_bf16(aq[1], b1, acc, 0, 0, 0);
        s[nf] = acc;
      }

      // ---- causal mask (scale already folded into Q; diagonal tile only) ----
      if (t == qt) {
        #pragma unroll
        for (int nf=0; nf<4; ++nf)
          #pragma unroll
          for (int r=0; r<4; ++r)
            if (nf*16 + lr > w*16 + lg*4 + r) s[nf][r] = -3.0e38f;
      }

      // ---- online softmax (rows live in 16-lane groups) ----
      float mx[4], rs[4], al[4];
      #pragma unroll
      for (int r=0;r<4;++r)
        mx[r] = fmaxf(fmaxf(s[0][r], s[1][r]), fmaxf(s[2][r], s[3][r]));
      #pragma unroll
      for (int st=1; st<16; st<<=1)
        #pragma unroll
        for (int r=0;r<4;++r)
          mx[r] = fmaxf(mx[r], __shfl_xor(mx[r], st));
      #pragma unroll
      for (int r=0;r<4;++r) {
        float mn = fmaxf(m[r], mx[r]);
        al[r] = __expf(m[r] - mn);
        m[r] = mn;
        rs[r] = 0.f;
      }
      #pragma unroll
      for (int nf=0; nf<4; ++nf)
        #pragma unroll
        for (int r=0;r<4;++r) {
          float p = __expf(s[nf][r] - m[r]);
          rs[r] += p;
          s[nf][r] = p;
        }
      #pragma unroll
      for (int st=1; st<16; st<<=1)
        #pragma unroll
        for (int r=0;r<4;++r)
          rs[r] += __shfl_xor(rs[r], st);
      #pragma unroll
      for (int r=0;r<4;++r) lsum[r] = lsum[r]*al[r] + rs[r];
      #pragma unroll
      for (int df=0; df<4; ++df)
        #pragma unroll
        for (int r=0;r<4;++r) o[df][r] *= al[r];

      // ---- P: D-layout regs -> bf16 LDS (per-wave), swizzled ----
      #pragma unroll
      for (int nf=0; nf<4; ++nf)
        #pragma unroll
        for (int r=0;r<4;++r) {
          int q = lg*4 + r;
          int k = nf*16 + lr;
          *(__bf16*)(Pw + q*128 + ((k*2) ^ ((q&7)<<4))) = (__bf16)s[nf][r];
        }

      // ---- PV: O[16 q][64 d] += P @ V ----
      {
        unsigned xq = (lr & 7) << 4;
        const char* pp = Pw + lr*128;
        bf16x8 pa0 = *(const bf16x8*)(pp + ((lg*16)      ^ xq));
        bf16x8 pa1 = *(const bf16x8*)(pp + ((64 + lg*16) ^ xq));
        #pragma unroll
        for (int df=0; df<4; ++df) {
          int d = df*16 + lr;
          unsigned xd = (d & 7) << 4;
          const char* vp = Vcur + d*128;
          bf16x8 vb0 = *(const bf16x8*)(vp + ((lg*16)      ^ xd));
          bf16x8 vb1 = *(const bf16x8*)(vp + ((64 + lg*16) ^ xd));
          o[df] = __builtin_amdgcn_mfma_f32_16x16x32_bf16(pa0, vb0, o[df], 0, 0, 0);
          o[df] = __builtin_amdgcn_mfma_f32_16x16x32_bf16(pa1, vb1, o[df], 0, 0, 0);
        }
      }
      __syncthreads();
    }

    // ---- epilogue: O / lsum -> global ----
    #pragma unroll
    for (int r=0;r<4;++r) {
      float inv = 1.0f / lsum[r];
      int qg = qt*64 + w*16 + lg*4 + r;
      float* op = O + ((size_t)(b*Lc + qg)*Hc + h)*Dc;
      #pragma unroll
      for (int df=0; df<4; ++df)
        op[df*16 + lr] = o[df][r] * inv;
    }
  } // pass loop
}

extern "C" void kernel_launch(void* const* d_in, const int* in_sizes, int n_in,
                              void* d_out, int out_size, void* d_ws, size_t ws_size,
                              hipStream_t stream) {
  const float* Q = (const float*)d_in[0];
  const float* K = (const float*)d_in[1];
  const float* V = (const float*)d_in[2];
  float* O = (float*)d_out;
  dim3 grid(Bc * Hc * NPAIR);   // 1024 blocks, 33 tiles each (balanced)
  dim3 block(256);
  fa_fwd<<<grid, block, 0, stream>>>(Q, K, V, O);
}

// Round 9
// 128.165 us; speedup vs baseline: 2.9321x; 1.1642x over previous
//
#include <hip/hip_runtime.h>
#include <hip/hip_bf16.h>

typedef __bf16 bf16x8 __attribute__((ext_vector_type(8)));
typedef float floatx4 __attribute__((ext_vector_type(4)));

#define Bc 4
#define Lc 2048
#define Sc 2048
#define Hc 16
#define Ec 64
#define Dc 64
#define NQT (Lc/64)      /* 32 strips of 64 q-rows */
#define NPAIR (NQT/2)    /* 16 pair-ids */

__device__ __forceinline__ bf16x8 pack8f(const float* f){
  bf16x8 r;
  #pragma unroll
  for (int i=0;i<8;++i) r[i] = (__bf16)f[i];
  return r;
}

// DPP lane-permute within each 16-lane row (VALU, no LDS pipe)
template<int CTRL>
__device__ __forceinline__ float dppf(float x){
  return __builtin_bit_cast(float,
    __builtin_amdgcn_update_dpp(0, __builtin_bit_cast(int, x), CTRL, 0xF, 0xF, true));
}
// 16-lane max/sum reduce: xor1, xor2, (xor4), (xor8) via quad_perm + mirrors
__device__ __forceinline__ float rowmax16(float x){
  x = fmaxf(x, dppf<0xB1>(x));    // quad_perm [1,0,3,2]  = xor1
  x = fmaxf(x, dppf<0x4E>(x));    // quad_perm [2,3,0,1]  = xor2
  x = fmaxf(x, dppf<0x141>(x));   // row_half_mirror      = xor4 (quads uniform)
  x = fmaxf(x, dppf<0x140>(x));   // row_mirror           = xor8 (halves uniform)
  return x;
}
__device__ __forceinline__ float rowsum16(float x){
  x += dppf<0xB1>(x);
  x += dppf<0x4E>(x);
  x += dppf<0x141>(x);
  x += dppf<0x140>(x);
  return x;
}

__global__ __launch_bounds__(256)
void fa_fwd(const float* __restrict__ Q, const float* __restrict__ K,
            const float* __restrict__ V, float* __restrict__ O)
{
  // XCD-contiguous remap (1024 % 8 == 0, bijective)
  int nid = blockIdx.x;
  int bid = (nid & 7) * ((int)gridDim.x >> 3) + (nid >> 3);
  int pid = bid & (NPAIR - 1);
  int h  = (bid >> 4) & (Hc - 1);
  int b  = bid >> 8;

  int tid  = threadIdx.x;
  int w    = tid >> 6;
  int lane = tid & 63;
  int lg   = lane >> 4;   // 0..3
  int lr   = lane & 15;   // 0..15

  __shared__ __align__(16) char Kl[2][64*128];
  __shared__ __align__(16) char Vl[2][64*128];    // transposed: Vt[d][k], swizzled
  __shared__ __align__(16) char Pl[4][16*64*2];   // per-wave P buffer
  char* Pw = Pl[w];

  // ---- staging thread mapping ----
  const int skr = tid >> 2, seg = tid & 3;   // K: row skr (0..63), 16-float chunk seg
  const int sd  = tid & 63, skb = tid >> 6;  // V: d-column sd (0..63), key-block skb (16 keys)
  const unsigned xk = (skr & 7) << 4;
  const unsigned xv = (sd  & 7) << 4;

  const float* Kb = K + ((size_t)(b*Sc)*Hc + h)*Ec;
  const float* Vb = V + ((size_t)(b*Sc)*Hc + h)*Dc;

  float kf[16], vf[16];

  // ---- two complementary causal strips: work = (pid+1) + (32-pid) = 33 tiles, constant ----
  #pragma unroll 1
  for (int pass=0; pass<2; ++pass) {
    const int qt = pass ? (NQT-1-pid) : pid;

    // ---- Q fragments, scale 1/8 folded in (A-layout: row=lr, k=32*c+8*lg+j) ----
    const int qrow = qt*64 + w*16 + lr;
    const float* qp = Q + ((size_t)(b*Lc + qrow)*Hc + h)*Ec;
    bf16x8 aq[2];
    {
      float tmp[8];
      #pragma unroll
      for (int c=0; c<2; ++c) {
        *(float4*)(tmp)   = *(const float4*)(qp + c*32 + lg*8);
        *(float4*)(tmp+4) = *(const float4*)(qp + c*32 + lg*8 + 4);
        #pragma unroll
        for (int i=0;i<8;++i) tmp[i] *= 0.125f;
        aq[c] = pack8f(tmp);
      }
    }

    floatx4 o[4];
    float m[4], lsum[4];
    #pragma unroll
    for (int i=0;i<4;++i){ o[i] = (floatx4){0.f,0.f,0.f,0.f}; m[i] = -3.0e38f; lsum[i] = 0.f; }

    // prefetch tile 0 into registers
    {
      const float* ks = Kb + (size_t)skr*Hc*Ec + seg*16;
      *(float4*)(kf)    = *(const float4*)(ks);
      *(float4*)(kf+4)  = *(const float4*)(ks+4);
      *(float4*)(kf+8)  = *(const float4*)(ks+8);
      *(float4*)(kf+12) = *(const float4*)(ks+12);
      const float* vs = Vb + (size_t)(skb*16)*Hc*Dc + sd;
      #pragma unroll
      for (int i=0;i<16;++i) vf[i] = vs[(size_t)i*Hc*Dc];
    }

    const int nt = qt + 1;
    for (int t = 0; t < nt; ++t) {
      char* Kcur = Kl[t&1];
      char* Vcur = Vl[t&1];

      // ---- write staged tile from registers (bf16, swizzled, wide) ----
      *(bf16x8*)(Kcur + skr*128 + ((seg*32)      ^ xk)) = pack8f(kf);
      *(bf16x8*)(Kcur + skr*128 + ((seg*32 + 16) ^ xk)) = pack8f(kf+8);
      *(bf16x8*)(Vcur + sd*128  + ((skb*32)      ^ xv)) = pack8f(vf);
      *(bf16x8*)(Vcur + sd*128  + ((skb*32 + 16) ^ xv)) = pack8f(vf+8);
      __syncthreads();

      // ---- async-stage split: issue next tile's global loads now ----
      if (t+1 < nt) {
        const float* ks = Kb + (size_t)((t+1)*64 + skr)*Hc*Ec + seg*16;
        *(float4*)(kf)    = *(const float4*)(ks);
        *(float4*)(kf+4)  = *(const float4*)(ks+4);
        *(float4*)(kf+8)  = *(const float4*)(ks+8);
        *(float4*)(kf+12) = *(const float4*)(ks+12);
        const float* vs = Vb + (size_t)((t+1)*64 + skb*16)*Hc*Dc + sd;
        #pragma unroll
        for (int i=0;i<16;++i) vf[i] = vs[(size_t)i*Hc*Dc];
      }

      // ---- QK^T: S[16 q][64 k] ----
      floatx4 s[4];
      #pragma unroll
      for (int nf=0; nf<4; ++nf) {
        int kr = nf*16 + lr;
        unsigned xr = (kr & 7) << 4;
        const char* kp = Kcur + kr*128;
        bf16x8 b0 = *(const bf16x8*)(kp + ((lg*16)      ^ xr));
        bf16x8 b1 = *(const bf16x8*)(kp + ((64 + lg*16) ^ xr));
        floatx4 acc = (floatx4){0.f,0.f,0.f,0.f};
        acc = __builtin_amdgcn_mfma_f32_16x16x32_bf16(aq[0], b0, acc, 0, 0, 0);
        acc = __builtin_amdgcn_mfma_f32_16x16x32_bf16(aq[1], b1, acc, 0, 0, 0);
        s[nf] = acc;
      }

      // ---- causal mask (scale already folded into Q; diagonal tile only) ----
      if (t == qt) {
        #pragma unroll
        for (int nf=0; nf<4; ++nf)
          #pragma unroll
          for (int r=0; r<4; ++r)
            if (nf*16 + lr > w*16 + lg*4 + r) s[nf][r] = -3.0e38f;
      }

      // ---- online softmax (16-lane reductions via DPP, no LDS pipe) ----
      float mx[4], rs[4], al[4];
      #pragma unroll
      for (int r=0;r<4;++r) {
        mx[r] = rowmax16(fmaxf(fmaxf(s[0][r], s[1][r]), fmaxf(s[2][r], s[3][r])));
        float mn = fmaxf(m[r], mx[r]);
        al[r] = __expf(m[r] - mn);
        m[r] = mn;
        rs[r] = 0.f;
      }
      #pragma unroll
      for (int nf=0; nf<4; ++nf)
        #pragma unroll
        for (int r=0;r<4;++r) {
          float p = __expf(s[nf][r] - m[r]);
          rs[r] += p;
          s[nf][r] = p;
        }
      #pragma unroll
      for (int r=0;r<4;++r) {
        rs[r] = rowsum16(rs[r]);
        lsum[r] = lsum[r]*al[r] + rs[r];
      }
      #pragma unroll
      for (int df=0; df<4; ++df)
        #pragma unroll
        for (int r=0;r<4;++r) o[df][r] *= al[r];

      // ---- P: D-layout regs -> bf16 LDS (per-wave), swizzled ----
      #pragma unroll
      for (int nf=0; nf<4; ++nf)
        #pragma unroll
        for (int r=0;r<4;++r) {
          int q = lg*4 + r;
          int k = nf*16 + lr;
          *(__bf16*)(Pw + q*128 + ((k*2) ^ ((q&7)<<4))) = (__bf16)s[nf][r];
        }

      // ---- PV: O[16 q][64 d] += P @ V ----
      {
        unsigned xq = (lr & 7) << 4;
        const char* pp = Pw + lr*128;
        bf16x8 pa0 = *(const bf16x8*)(pp + ((lg*16)      ^ xq));
        bf16x8 pa1 = *(const bf16x8*)(pp + ((64 + lg*16) ^ xq));
        #pragma unroll
        for (int df=0; df<4; ++df) {
          int d = df*16 + lr;
          unsigned xd = (d & 7) << 4;
          const char* vp = Vcur + d*128;
          bf16x8 vb0 = *(const bf16x8*)(vp + ((lg*16)      ^ xd));
          bf16x8 vb1 = *(const bf16x8*)(vp + ((64 + lg*16) ^ xd));
          o[df] = __builtin_amdgcn_mfma_f32_16x16x32_bf16(pa0, vb0, o[df], 0, 0, 0);
          o[df] = __builtin_amdgcn_mfma_f32_16x16x32_bf16(pa1, vb1, o[df], 0, 0, 0);
        }
      }
      __syncthreads();
    }

    // ---- epilogue: O / lsum -> global ----
    #pragma unroll
    for (int r=0;r<4;++r) {
      float inv = 1.0f / lsum[r];
      int qg = qt*64 + w*16 + lg*4 + r;
      float* op = O + ((size_t)(b*Lc + qg)*Hc + h)*Dc;
      #pragma unroll
      for (int df=0; df<4; ++df)
        op[df*16 + lr] = o[df][r] * inv;
    }
  } // pass loop
}

extern "C" void kernel_launch(void* const* d_in, const int* in_sizes, int n_in,
                              void* d_out, int out_size, void* d_ws, size_t ws_size,
                              hipStream_t stream) {
  const float* Q = (const float*)d_in[0];
  const float* K = (const float*)d_in[1];
  const float* V = (const float*)d_in[2];
  float* O = (float*)d_out;
  dim3 grid(Bc * Hc * NPAIR);   // 1024 blocks, 33 tiles each (balanced)
  dim3 block(256);
  fa_fwd<<<grid, block, 0, stream>>>(Q, K, V, O);
}

// Round 10
// 120.114 us; speedup vs baseline: 3.1286x; 1.0670x over previous
//
#include <hip/hip_runtime.h>
#include <hip/hip_bf16.h>

typedef __bf16 bf16x8 __attribute__((ext_vector_type(8)));
typedef float floatx4 __attribute__((ext_vector_type(4)));

#define Bc 4
#define Lc 2048
#define Sc 2048
#define Hc 16
#define Ec 64
#define Dc 64
#define QB 128
#define NQTB (Lc/QB)     /* 16 strips of 128 q-rows */
#define NPAIRB (NQTB/2)  /* 8 pair-ids */

__device__ __forceinline__ bf16x8 pack8f(const float* f){
  bf16x8 r;
  #pragma unroll
  for (int i=0;i<8;++i) r[i] = (__bf16)f[i];
  return r;
}

// DPP lane-permute within each 16-lane row (VALU, no LDS pipe)
template<int CTRL>
__device__ __forceinline__ float dppf(float x){
  return __builtin_bit_cast(float,
    __builtin_amdgcn_update_dpp(0, __builtin_bit_cast(int, x), CTRL, 0xF, 0xF, true));
}
__device__ __forceinline__ float rowmax16(float x){
  x = fmaxf(x, dppf<0xB1>(x));    // quad_perm [1,0,3,2]  = xor1
  x = fmaxf(x, dppf<0x4E>(x));    // quad_perm [2,3,0,1]  = xor2
  x = fmaxf(x, dppf<0x141>(x));   // row_half_mirror      = xor4
  x = fmaxf(x, dppf<0x140>(x));   // row_mirror           = xor8
  return x;
}
__device__ __forceinline__ float rowsum16(float x){
  x += dppf<0xB1>(x);
  x += dppf<0x4E>(x);
  x += dppf<0x141>(x);
  x += dppf<0x140>(x);
  return x;
}

__global__ __launch_bounds__(256)
void fa_fwd(const float* __restrict__ Q, const float* __restrict__ K,
            const float* __restrict__ V, float* __restrict__ O)
{
  // XCD-contiguous remap (512 % 8 == 0, bijective)
  int nid = blockIdx.x;
  int bid = (nid & 7) * ((int)gridDim.x >> 3) + (nid >> 3);
  int pid = bid & (NPAIRB - 1);
  int h  = (bid >> 3) & (Hc - 1);
  int b  = bid >> 7;

  int tid  = threadIdx.x;
  int w    = tid >> 6;
  int lane = tid & 63;
  int lg   = lane >> 4;   // 0..3
  int lr   = lane & 15;   // 0..15

  __shared__ __align__(16) char Kl[2][64*128];
  __shared__ __align__(16) char Vl[2][64*128];    // transposed: Vt[d][k], swizzled
  __shared__ __align__(16) char Pl[4][16*64*2];   // per-wave P buffer, reused per q-set
  char* Pw = Pl[w];

  // ---- staging thread mapping ----
  const int skr = tid >> 2, seg = tid & 3;   // K: row skr (0..63), 16-float chunk seg
  const int sd  = tid & 63, skb = tid >> 6;  // V: d-column sd (0..63), key-block skb (16 keys)
  const unsigned xk = (skr & 7) << 4;
  const unsigned xv = (sd  & 7) << 4;

  const float* Kb = K + ((size_t)(b*Sc)*Hc + h)*Ec;
  const float* Vb = V + ((size_t)(b*Sc)*Hc + h)*Dc;

  float kf[16], vf[16];

  // ---- two complementary strips: work = (2*pid+2) + (2*(15-pid)+2) = 34 tiles, constant ----
  #pragma unroll 1
  for (int pass=0; pass<2; ++pass) {
    const int qtb = pass ? (NQTB-1-pid) : pid;
    const int q0w = qtb*QB + w*32;   // this wave's first q row (32 rows, 2 sets of 16)

    // ---- Q fragments for both 16-row sets, scale 1/8 folded in ----
    bf16x8 aq[2][2];
    #pragma unroll
    for (int s2=0; s2<2; ++s2) {
      const float* qp = Q + ((size_t)(b*Lc + q0w + s2*16 + lr)*Hc + h)*Ec;
      float tmp[8];
      #pragma unroll
      for (int c=0; c<2; ++c) {
        *(float4*)(tmp)   = *(const float4*)(qp + c*32 + lg*8);
        *(float4*)(tmp+4) = *(const float4*)(qp + c*32 + lg*8 + 4);
        #pragma unroll
        for (int i=0;i<8;++i) tmp[i] *= 0.125f;
        aq[s2][c] = pack8f(tmp);
      }
    }

    floatx4 o[2][4];
    float m[2][4], lsum[2][4];
    #pragma unroll
    for (int s2=0; s2<2; ++s2)
      #pragma unroll
      for (int i=0;i<4;++i){ o[s2][i] = (floatx4){0.f,0.f,0.f,0.f}; m[s2][i] = -3.0e38f; lsum[s2][i] = 0.f; }

    // prefetch tile 0 into registers
    {
      const float* ks = Kb + (size_t)skr*Hc*Ec + seg*16;
      *(float4*)(kf)    = *(const float4*)(ks);
      *(float4*)(kf+4)  = *(const float4*)(ks+4);
      *(float4*)(kf+8)  = *(const float4*)(ks+8);
      *(float4*)(kf+12) = *(const float4*)(ks+12);
      const float* vs = Vb + (size_t)(skb*16)*Hc*Dc + sd;
      #pragma unroll
      for (int i=0;i<16;++i) vf[i] = vs[(size_t)i*Hc*Dc];
    }

    const int nt = 2*qtb + 2;
    for (int t = 0; t < nt; ++t) {
      char* Kcur = Kl[t&1];
      char* Vcur = Vl[t&1];

      // ---- write staged tile from registers (bf16, swizzled, wide) ----
      *(bf16x8*)(Kcur + skr*128 + ((seg*32)      ^ xk)) = pack8f(kf);
      *(bf16x8*)(Kcur + skr*128 + ((seg*32 + 16) ^ xk)) = pack8f(kf+8);
      *(bf16x8*)(Vcur + sd*128  + ((skb*32)      ^ xv)) = pack8f(vf);
      *(bf16x8*)(Vcur + sd*128  + ((skb*32 + 16) ^ xv)) = pack8f(vf+8);
      __syncthreads();

      // ---- async-stage split: issue next tile's global loads now ----
      if (t+1 < nt) {
        const float* ks = Kb + (size_t)((t+1)*64 + skr)*Hc*Ec + seg*16;
        *(float4*)(kf)    = *(const float4*)(ks);
        *(float4*)(kf+4)  = *(const float4*)(ks+4);
        *(float4*)(kf+8)  = *(const float4*)(ks+8);
        *(float4*)(kf+12) = *(const float4*)(ks+12);
        const float* vs = Vb + (size_t)((t+1)*64 + skb*16)*Hc*Dc + sd;
        #pragma unroll
        for (int i=0;i<16;++i) vf[i] = vs[(size_t)i*Hc*Dc];
      }

      // ---- per-wave skip: tile entirely above this wave's 32 rows ----
      if (t*64 <= q0w + 31) {
        const int t64 = t*64;
        const bool needmask = (t64 + 63 > q0w);

        #pragma unroll
        for (int s2=0; s2<2; ++s2) {
          // ---- QK^T: S[16 q][64 k] ----
          floatx4 s[4];
          #pragma unroll
          for (int nf=0; nf<4; ++nf) {
            int kr = nf*16 + lr;
            unsigned xr = (kr & 7) << 4;
            const char* kp = Kcur + kr*128;
            bf16x8 b0 = *(const bf16x8*)(kp + ((lg*16)      ^ xr));
            bf16x8 b1 = *(const bf16x8*)(kp + ((64 + lg*16) ^ xr));
            floatx4 acc = (floatx4){0.f,0.f,0.f,0.f};
            acc = __builtin_amdgcn_mfma_f32_16x16x32_bf16(aq[s2][0], b0, acc, 0, 0, 0);
            acc = __builtin_amdgcn_mfma_f32_16x16x32_bf16(aq[s2][1], b1, acc, 0, 0, 0);
            s[nf] = acc;
          }

          // ---- causal mask (scale folded into Q; global indices) ----
          if (needmask) {
            const int qq = q0w + s2*16 + lg*4;
            #pragma unroll
            for (int nf=0; nf<4; ++nf)
              #pragma unroll
              for (int r=0; r<4; ++r)
                if (t64 + nf*16 + lr > qq + r) s[nf][r] = -3.0e38f;
          }

          // ---- online softmax (16-lane reductions via DPP) ----
          float mx[4], rs[4], al[4];
          #pragma unroll
          for (int r=0;r<4;++r) {
            mx[r] = rowmax16(fmaxf(fmaxf(s[0][r], s[1][r]), fmaxf(s[2][r], s[3][r])));
            float mn = fmaxf(m[s2][r], mx[r]);
            al[r] = __expf(m[s2][r] - mn);
            m[s2][r] = mn;
            rs[r] = 0.f;
          }
          #pragma unroll
          for (int nf=0; nf<4; ++nf)
            #pragma unroll
            for (int r=0;r<4;++r) {
              float p = __expf(s[nf][r] - m[s2][r]);
              rs[r] += p;
              s[nf][r] = p;
            }
          #pragma unroll
          for (int r=0;r<4;++r) {
            rs[r] = rowsum16(rs[r]);
            lsum[s2][r] = lsum[s2][r]*al[r] + rs[r];
          }
          #pragma unroll
          for (int df=0; df<4; ++df)
            #pragma unroll
            for (int r=0;r<4;++r) o[s2][df][r] *= al[r];

          // ---- P: D-layout regs -> bf16 LDS (per-wave, reused per set) ----
          #pragma unroll
          for (int nf=0; nf<4; ++nf)
            #pragma unroll
            for (int r=0;r<4;++r) {
              int q = lg*4 + r;
              int k = nf*16 + lr;
              *(__bf16*)(Pw + q*128 + ((k*2) ^ ((q&7)<<4))) = (__bf16)s[nf][r];
            }

          // ---- PV: O[16 q][64 d] += P @ V ----
          {
            unsigned xq = (lr & 7) << 4;
            const char* pp = Pw + lr*128;
            bf16x8 pa0 = *(const bf16x8*)(pp + ((lg*16)      ^ xq));
            bf16x8 pa1 = *(const bf16x8*)(pp + ((64 + lg*16) ^ xq));
            #pragma unroll
            for (int df=0; df<4; ++df) {
              int d = df*16 + lr;
              unsigned xd = (d & 7) << 4;
              const char* vp = Vcur + d*128;
              bf16x8 vb0 = *(const bf16x8*)(vp + ((lg*16)      ^ xd));
              bf16x8 vb1 = *(const bf16x8*)(vp + ((64 + lg*16) ^ xd));
              o[s2][df] = __builtin_amdgcn_mfma_f32_16x16x32_bf16(pa0, vb0, o[s2][df], 0, 0, 0);
              o[s2][df] = __builtin_amdgcn_mfma_f32_16x16x32_bf16(pa1, vb1, o[s2][df], 0, 0, 0);
            }
          }
        } // q-set loop
      }
      __syncthreads();
    }

    // ---- epilogue: O / lsum -> global ----
    #pragma unroll
    for (int s2=0; s2<2; ++s2)
      #pragma unroll
      for (int r=0;r<4;++r) {
        float inv = 1.0f / lsum[s2][r];
        int qg = q0w + s2*16 + lg*4 + r;
        float* op = O + ((size_t)(b*Lc + qg)*Hc + h)*Dc;
        #pragma unroll
        for (int df=0; df<4; ++df)
          op[df*16 + lr] = o[s2][df][r] * inv;
      }
  } // pass loop
}

extern "C" void kernel_launch(void* const* d_in, const int* in_sizes, int n_in,
                              void* d_out, int out_size, void* d_ws, size_t ws_size,
                              hipStream_t stream) {
  const float* Q = (const float*)d_in[0];
  const float* K = (const float*)d_in[1];
  const float* V = (const float*)d_in[2];
  float* O = (float*)d_out;
  dim3 grid(Bc * Hc * NPAIRB);   // 512 blocks, 34 tiles each (balanced)
  dim3 block(256);
  fa_fwd<<<grid, block, 0, stream>>>(Q, K, V, O);
}

// Round 11
// 111.698 us; speedup vs baseline: 3.3644x; 1.0753x over previous
//
#include <hip/hip_runtime.h>
#include <hip/hip_bf16.h>

typedef __bf16 bf16x8 __attribute__((ext_vector_type(8)));
typedef float floatx4 __attribute__((ext_vector_type(4)));
typedef unsigned int u32;

#define Bc 4
#define Lc 2048
#define Sc 2048
#define Hc 16
#define Ec 64
#define Dc 64
#define NQT (Lc/64)      /* 32 q-strips of 64 rows */
#define NPAIR (NQT/2)    /* 16 pair-ids */
#define NT (Sc/64)       /* 32 kv tiles */
#define TILEB 8192       /* bytes per bf16 tile image (64x64x2) */
#define WSK ((size_t)Bc*Hc*NT*TILEB)   /* 16 MB for K images */
#define WSNEED (2*WSK)                 /* 32 MB total */

__device__ __forceinline__ bf16x8 pack8f(const float* f){
  bf16x8 r;
  #pragma unroll
  for (int i=0;i<8;++i) r[i] = (__bf16)f[i];
  return r;
}

// DPP lane-permute within each 16-lane row (VALU, no LDS pipe)
template<int CTRL>
__device__ __forceinline__ float dppf(float x){
  return __builtin_bit_cast(float,
    __builtin_amdgcn_update_dpp(0, __builtin_bit_cast(int, x), CTRL, 0xF, 0xF, true));
}
__device__ __forceinline__ float rowmax16(float x){
  x = fmaxf(x, dppf<0xB1>(x));    // xor1
  x = fmaxf(x, dppf<0x4E>(x));    // xor2
  x = fmaxf(x, dppf<0x141>(x));   // xor4 (row_half_mirror)
  x = fmaxf(x, dppf<0x140>(x));   // xor8 (row_mirror)
  return x;
}
__device__ __forceinline__ float rowsum16(float x){
  x += dppf<0xB1>(x);
  x += dppf<0x4E>(x);
  x += dppf<0x141>(x);
  x += dppf<0x140>(x);
  return x;
}

__device__ __forceinline__ void gload16(const void* g, void* l){
  __builtin_amdgcn_global_load_lds(
      (const __attribute__((address_space(1))) u32*)g,
      (__attribute__((address_space(3))) u32*)l, 16, 0, 0);
}

// ---- prepass: K,V f32 -> bf16 pre-swizzled LDS tile images in workspace ----
__global__ __launch_bounds__(256)
void prep(const float* __restrict__ K, const float* __restrict__ V,
          char* __restrict__ ws)
{
  const int t = blockIdx.x*256 + threadIdx.x;   // 0 .. 2*2^20-1
  if (t < (1<<20)) {
    // K image: row r (key), chunk c holds elems c*8..c*8+7, stored at (c^(r&7))*16
    const int c = t & 7, r = (t>>3) & 63, tile = (t>>9) & 31, h = (t>>14) & 15, b = t>>18;
    const float* src = K + ((size_t)((b*Sc + tile*64 + r))*Hc + h)*Ec + c*8;
    float tmp[8];
    *(float4*)(tmp)   = *(const float4*)(src);
    *(float4*)(tmp+4) = *(const float4*)(src + 4);
    char* dst = ws + (size_t)((b*Hc + h)*NT + tile)*TILEB + r*128 + ((c ^ (r&7))<<4);
    *(bf16x8*)dst = pack8f(tmp);
  } else {
    // V image (transposed): row d, chunk c holds keys c*8..c*8+7, stored at (c^(d&7))*16
    const int u = t - (1<<20);
    const int d = u & 63, c = (u>>6) & 7, tile = (u>>9) & 31, h = (u>>14) & 15, b = u>>18;
    const float* src = V + ((size_t)((b*Sc + tile*64 + c*8))*Hc + h)*Dc + d;
    bf16x8 v;
    #pragma unroll
    for (int kk=0; kk<8; ++kk) v[kk] = (__bf16)src[(size_t)kk*Hc*Dc];
    char* dst = ws + WSK + (size_t)((b*Hc + h)*NT + tile)*TILEB + d*128 + ((c ^ (d&7))<<4);
    *(bf16x8*)dst = v;
  }
}

// ---- main kernel: global_load_lds staging from pre-swizzled images ----
__global__ __launch_bounds__(256)
void fa_fwd(const float* __restrict__ Q, const char* __restrict__ ws,
            float* __restrict__ O)
{
  // XCD-contiguous remap (1024 % 8 == 0, bijective)
  int nid = blockIdx.x;
  int bid = (nid & 7) * ((int)gridDim.x >> 3) + (nid >> 3);
  int pid = bid & (NPAIR - 1);
  int h  = (bid >> 4) & (Hc - 1);
  int b  = bid >> 8;

  int tid  = threadIdx.x;
  int w    = tid >> 6;
  int lane = tid & 63;
  int lg   = lane >> 4;   // 0..3
  int lr   = lane & 15;   // 0..15

  __shared__ __align__(16) char Kl[2][64*128];
  __shared__ __align__(16) char Vl[2][64*128];    // transposed: Vt[d][k], swizzled
  __shared__ __align__(16) char Pl[4][16*64*2];   // per-wave P buffer
  char* Pw = Pl[w];

  const char* gK = ws +        (size_t)((b*Hc + h)*NT)*TILEB;
  const char* gV = ws + WSK +  (size_t)((b*Hc + h)*NT)*TILEB;
  const int soff = w*2048 + lane*16;   // this lane's share of an 8KB tile image

  // ---- two complementary causal strips: (pid+1) + (32-pid) = 33 tiles, constant ----
  #pragma unroll 1
  for (int pass=0; pass<2; ++pass) {
    const int qt = pass ? (NQT-1-pid) : pid;

    // ---- Q fragments, scale 1/8 folded in (A-layout: row=lr, k=32*c+8*lg+j) ----
    const int qrow = qt*64 + w*16 + lr;
    const float* qp = Q + ((size_t)(b*Lc + qrow)*Hc + h)*Ec;
    bf16x8 aq[2];
    {
      float tmp[8];
      #pragma unroll
      for (int c=0; c<2; ++c) {
        *(float4*)(tmp)   = *(const float4*)(qp + c*32 + lg*8);
        *(float4*)(tmp+4) = *(const float4*)(qp + c*32 + lg*8 + 4);
        #pragma unroll
        for (int i=0;i<8;++i) tmp[i] *= 0.125f;
        aq[c] = pack8f(tmp);
      }
    }

    floatx4 o[4];
    float m[4], lsum[4];
    #pragma unroll
    for (int i=0;i<4;++i){ o[i] = (floatx4){0.f,0.f,0.f,0.f}; m[i] = -3.0e38f; lsum[i] = 0.f; }

    // stage tile 0
    {
      const char* sK = gK + soff;
      const char* sV = gV + soff;
      gload16(sK,        &Kl[0][w*2048]);
      gload16(sK + 1024, &Kl[0][w*2048 + 1024]);
      gload16(sV,        &Vl[0][w*2048]);
      gload16(sV + 1024, &Vl[0][w*2048 + 1024]);
    }
    __syncthreads();   // drains vmcnt(0): tile 0 resident

    const int nt = qt + 1;
    for (int t = 0; t < nt; ++t) {
      char* Kcur = Kl[t&1];
      char* Vcur = Vl[t&1];

      // ---- issue next tile's staging into the other buffer ----
      if (t+1 < nt) {
        const int nb = (t+1)&1;
        const char* sK = gK + (size_t)(t+1)*TILEB + soff;
        const char* sV = gV + (size_t)(t+1)*TILEB + soff;
        gload16(sK,        &Kl[nb][w*2048]);
        gload16(sK + 1024, &Kl[nb][w*2048 + 1024]);
        gload16(sV,        &Vl[nb][w*2048]);
        gload16(sV + 1024, &Vl[nb][w*2048 + 1024]);
      }

      // ---- QK^T: S[16 q][64 k] ----
      floatx4 s[4];
      #pragma unroll
      for (int nf=0; nf<4; ++nf) {
        int kr = nf*16 + lr;
        unsigned xr = (kr & 7) << 4;
        const char* kp = Kcur + kr*128;
        bf16x8 b0 = *(const bf16x8*)(kp + ((lg*16)      ^ xr));
        bf16x8 b1 = *(const bf16x8*)(kp + ((64 + lg*16) ^ xr));
        floatx4 acc = (floatx4){0.f,0.f,0.f,0.f};
        acc = __builtin_amdgcn_mfma_f32_16x16x32_bf16(aq[0], b0, acc, 0, 0, 0);
        acc = __builtin_amdgcn_mfma_f32_16x16x32_bf16(aq[1], b1, acc, 0, 0, 0);
        s[nf] = acc;
      }

      // ---- causal mask (scale folded into Q; diagonal tile only) ----
      if (t == qt) {
        #pragma unroll
        for (int nf=0; nf<4; ++nf)
          #pragma unroll
          for (int r=0; r<4; ++r)
            if (nf*16 + lr > w*16 + lg*4 + r) s[nf][r] = -3.0e38f;
      }

      // ---- online softmax (16-lane reductions via DPP) ----
      float mx[4], rs[4], al[4];
      #pragma unroll
      for (int r=0;r<4;++r) {
        mx[r] = rowmax16(fmaxf(fmaxf(s[0][r], s[1][r]), fmaxf(s[2][r], s[3][r])));
        float mn = fmaxf(m[r], mx[r]);
        al[r] = __expf(m[r] - mn);
        m[r] = mn;
        rs[r] = 0.f;
      }
      #pragma unroll
      for (int nf=0; nf<4; ++nf)
        #pragma unroll
        for (int r=0;r<4;++r) {
          float p = __expf(s[nf][r] - m[r]);
          rs[r] += p;
          s[nf][r] = p;
        }
      #pragma unroll
      for (int r=0;r<4;++r) {
        rs[r] = rowsum16(rs[r]);
        lsum[r] = lsum[r]*al[r] + rs[r];
      }
      #pragma unroll
      for (int df=0; df<4; ++df)
        #pragma unroll
        for (int r=0;r<4;++r) o[df][r] *= al[r];

      // ---- P: D-layout regs -> bf16 LDS (per-wave), swizzled ----
      #pragma unroll
      for (int nf=0; nf<4; ++nf)
        #pragma unroll
        for (int r=0;r<4;++r) {
          int q = lg*4 + r;
          int k = nf*16 + lr;
          *(__bf16*)(Pw + q*128 + ((k*2) ^ ((q&7)<<4))) = (__bf16)s[nf][r];
        }

      // ---- PV: O[16 q][64 d] += P @ V ----
      {
        unsigned xq = (lr & 7) << 4;
        const char* pp = Pw + lr*128;
        bf16x8 pa0 = *(const bf16x8*)(pp + ((lg*16)      ^ xq));
        bf16x8 pa1 = *(const bf16x8*)(pp + ((64 + lg*16) ^ xq));
        #pragma unroll
        for (int df=0; df<4; ++df) {
          int d = df*16 + lr;
          unsigned xd = (d & 7) << 4;
          const char* vp = Vcur + d*128;
          bf16x8 vb0 = *(const bf16x8*)(vp + ((lg*16)      ^ xd));
          bf16x8 vb1 = *(const bf16x8*)(vp + ((64 + lg*16) ^ xd));
          o[df] = __builtin_amdgcn_mfma_f32_16x16x32_bf16(pa0, vb0, o[df], 0, 0, 0);
          o[df] = __builtin_amdgcn_mfma_f32_16x16x32_bf16(pa1, vb1, o[df], 0, 0, 0);
        }
      }
      __syncthreads();   // drains: next-tile loads landed, all reads of old buffer done
    }

    // ---- epilogue: O / lsum -> global ----
    #pragma unroll
    for (int r=0;r<4;++r) {
      float inv = 1.0f / lsum[r];
      int qg = qt*64 + w*16 + lg*4 + r;
      float* op = O + ((size_t)(b*Lc + qg)*Hc + h)*Dc;
      #pragma unroll
      for (int df=0; df<4; ++df)
        op[df*16 + lr] = o[df][r] * inv;
    }
  } // pass loop
}

// ---- fallback (round-10 kernel, used only if ws is too small) ----
#define QB 128
#define NQTB (Lc/QB)
#define NPAIRB (NQTB/2)

__global__ __launch_bounds__(256)
void fa_fwd_fb(const float* __restrict__ Q, const float* __restrict__ K,
               const float* __restrict__ V, float* __restrict__ O)
{
  int nid = blockIdx.x;
  int bid = (nid & 7) * ((int)gridDim.x >> 3) + (nid >> 3);
  int pid = bid & (NPAIRB - 1);
  int h  = (bid >> 3) & (Hc - 1);
  int b  = bid >> 7;

  int tid  = threadIdx.x;
  int w    = tid >> 6;
  int lane = tid & 63;
  int lg   = lane >> 4;
  int lr   = lane & 15;

  __shared__ __align__(16) char Kl[2][64*128];
  __shared__ __align__(16) char Vl[2][64*128];
  __shared__ __align__(16) char Pl[4][16*64*2];
  char* Pw = Pl[w];

  const int skr = tid >> 2, seg = tid & 3;
  const int sd  = tid & 63, skb = tid >> 6;
  const unsigned xk = (skr & 7) << 4;
  const unsigned xv = (sd  & 7) << 4;

  const float* Kb = K + ((size_t)(b*Sc)*Hc + h)*Ec;
  const float* Vb = V + ((size_t)(b*Sc)*Hc + h)*Dc;

  float kf[16], vf[16];

  #pragma unroll 1
  for (int pass=0; pass<2; ++pass) {
    const int qtb = pass ? (NQTB-1-pid) : pid;
    const int q0w = qtb*QB + w*32;

    bf16x8 aq[2][2];
    #pragma unroll
    for (int s2=0; s2<2; ++s2) {
      const float* qp = Q + ((size_t)(b*Lc + q0w + s2*16 + lr)*Hc + h)*Ec;
      float tmp[8];
      #pragma unroll
      for (int c=0; c<2; ++c) {
        *(float4*)(tmp)   = *(const float4*)(qp + c*32 + lg*8);
        *(float4*)(tmp+4) = *(const float4*)(qp + c*32 + lg*8 + 4);
        #pragma unroll
        for (int i=0;i<8;++i) tmp[i] *= 0.125f;
        aq[s2][c] = pack8f(tmp);
      }
    }

    floatx4 o[2][4];
    float m[2][4], lsum[2][4];
    #pragma unroll
    for (int s2=0; s2<2; ++s2)
      #pragma unroll
      for (int i=0;i<4;++i){ o[s2][i] = (floatx4){0.f,0.f,0.f,0.f}; m[s2][i] = -3.0e38f; lsum[s2][i] = 0.f; }

    {
      const float* ks = Kb + (size_t)skr*Hc*Ec + seg*16;
      *(float4*)(kf)    = *(const float4*)(ks);
      *(float4*)(kf+4)  = *(const float4*)(ks+4);
      *(float4*)(kf+8)  = *(const float4*)(ks+8);
      *(float4*)(kf+12) = *(const float4*)(ks+12);
      const float* vs = Vb + (size_t)(skb*16)*Hc*Dc + sd;
      #pragma unroll
      for (int i=0;i<16;++i) vf[i] = vs[(size_t)i*Hc*Dc];
    }

    const int nt = 2*qtb + 2;
    for (int t = 0; t < nt; ++t) {
      char* Kcur = Kl[t&1];
      char* Vcur = Vl[t&1];

      *(bf16x8*)(Kcur + skr*128 + ((seg*32)      ^ xk)) = pack8f(kf);
      *(bf16x8*)(Kcur + skr*128 + ((seg*32 + 16) ^ xk)) = pack8f(kf+8);
      *(bf16x8*)(Vcur + sd*128  + ((skb*32)      ^ xv)) = pack8f(vf);
      *(bf16x8*)(Vcur + sd*128  + ((skb*32 + 16) ^ xv)) = pack8f(vf+8);
      __syncthreads();

      if (t+1 < nt) {
        const float* ks = Kb + (size_t)((t+1)*64 + skr)*Hc*Ec + seg*16;
        *(float4*)(kf)    = *(const float4*)(ks);
        *(float4*)(kf+4)  = *(const float4*)(ks+4);
        *(float4*)(kf+8)  = *(const float4*)(ks+8);
        *(float4*)(kf+12) = *(const float4*)(ks+12);
        const float* vs = Vb + (size_t)((t+1)*64 + skb*16)*Hc*Dc + sd;
        #pragma unroll
        for (int i=0;i<16;++i) vf[i] = vs[(size_t)i*Hc*Dc];
      }

      if (t*64 <= q0w + 31) {
        const int t64 = t*64;
        const bool needmask = (t64 + 63 > q0w);

        #pragma unroll
        for (int s2=0; s2<2; ++s2) {
          floatx4 s[4];
          #pragma unroll
          for (int nf=0; nf<4; ++nf) {
            int kr = nf*16 + lr;
            unsigned xr = (kr & 7) << 4;
            const char* kp = Kcur + kr*128;
            bf16x8 b0 = *(const bf16x8*)(kp + ((lg*16)      ^ xr));
            bf16x8 b1 = *(const bf16x8*)(kp + ((64 + lg*16) ^ xr));
            floatx4 acc = (floatx4){0.f,0.f,0.f,0.f};
            acc = __builtin_amdgcn_mfma_f32_16x16x32_bf16(aq[s2][0], b0, acc, 0, 0, 0);
            acc = __builtin_amdgcn_mfma_f32_16x16x32_bf16(aq[s2][1], b1, acc, 0, 0, 0);
            s[nf] = acc;
          }

          if (needmask) {
            const int qq = q0w + s2*16 + lg*4;
            #pragma unroll
            for (int nf=0; nf<4; ++nf)
              #pragma unroll
              for (int r=0; r<4; ++r)
                if (t64 + nf*16 + lr > qq + r) s[nf][r] = -3.0e38f;
          }

          float mx[4], rs[4], al[4];
          #pragma unroll
          for (int r=0;r<4;++r) {
            mx[r] = rowmax16(fmaxf(fmaxf(s[0][r], s[1][r]), fmaxf(s[2][r], s[3][r])));
            float mn = fmaxf(m[s2][r], mx[r]);
            al[r] = __expf(m[s2][r] - mn);
            m[s2][r] = mn;
            rs[r] = 0.f;
          }
          #pragma unroll
          for (int nf=0; nf<4; ++nf)
            #pragma unroll
            for (int r=0;r<4;++r) {
              float p = __expf(s[nf][r] - m[s2][r]);
              rs[r] += p;
              s[nf][r] = p;
            }
          #pragma unroll
          for (int r=0;r<4;++r) {
            rs[r] = rowsum16(rs[r]);
            lsum[s2][r] = lsum[s2][r]*al[r] + rs[r];
          }
          #pragma unroll
          for (int df=0; df<4; ++df)
            #pragma unroll
            for (int r=0;r<4;++r) o[s2][df][r] *= al[r];

          #pragma unroll
          for (int nf=0; nf<4; ++nf)
            #pragma unroll
            for (int r=0;r<4;++r) {
              int q = lg*4 + r;
              int k = nf*16 + lr;
              *(__bf16*)(Pw + q*128 + ((k*2) ^ ((q&7)<<4))) = (__bf16)s[nf][r];
            }

          {
            unsigned xq = (lr & 7) << 4;
            const char* pp = Pw + lr*128;
            bf16x8 pa0 = *(const bf16x8*)(pp + ((lg*16)      ^ xq));
            bf16x8 pa1 = *(const bf16x8*)(pp + ((64 + lg*16) ^ xq));
            #pragma unroll
            for (int df=0; df<4; ++df) {
              int d = df*16 + lr;
              unsigned xd = (d & 7) << 4;
              const char* vp = Vcur + d*128;
              bf16x8 vb0 = *(const bf16x8*)(vp + ((lg*16)      ^ xd));
              bf16x8 vb1 = *(const bf16x8*)(vp + ((64 + lg*16) ^ xd));
              o[s2][df] = __builtin_amdgcn_mfma_f32_16x16x32_bf16(pa0, vb0, o[s2][df], 0, 0, 0);
              o[s2][df] = __builtin_amdgcn_mfma_f32_16x16x32_bf16(pa1, vb1, o[s2][df], 0, 0, 0);
            }
          }
        }
      }
      __syncthreads();
    }

    #pragma unroll
    for (int s2=0; s2<2; ++s2)
      #pragma unroll
      for (int r=0;r<4;++r) {
        float inv = 1.0f / lsum[s2][r];
        int qg = q0w + s2*16 + lg*4 + r;
        float* op = O + ((size_t)(b*Lc + qg)*Hc + h)*Dc;
        #pragma unroll
        for (int df=0; df<4; ++df)
          op[df*16 + lr] = o[s2][df][r] * inv;
      }
  }
}

extern "C" void kernel_launch(void* const* d_in, const int* in_sizes, int n_in,
                              void* d_out, int out_size, void* d_ws, size_t ws_size,
                              hipStream_t stream) {
  const float* Q = (const float*)d_in[0];
  const float* K = (const float*)d_in[1];
  const float* V = (const float*)d_in[2];
  float* O = (float*)d_out;

  if (ws_size >= WSNEED) {
    char* ws = (char*)d_ws;
    prep<<<dim3((2u<<20)/256), dim3(256), 0, stream>>>(K, V, ws);
    fa_fwd<<<dim3(Bc * Hc * NPAIR), dim3(256), 0, stream>>>(Q, ws, O);
  } else {
    fa_fwd_fb<<<dim3(Bc * Hc * NPAIRB), dim3(256), 0, stream>>>(Q, K, V, O);
  }
}